// Round 1
// baseline (5414.231 us; speedup 1.0000x reference)
//
#include <hip/hip_runtime.h>

// SRU forward, MI355X. B=16, T=2048, D=1024, L=4.
// h stored as bf16 hi/lo split pair (f32-equivalent precision, MFMA-consumable).
// GEMM: U = h @ W_l via 3-product split-bf16 MFMA (AhBh + AhBl + AlBh), f32 acc.
// Scan: sequential over T per (b,d) chain, fused sigmoid/tanh/highway, in-place h.

typedef float f32x4 __attribute__((ext_vector_type(4)));
typedef short s16x8 __attribute__((ext_vector_type(8)));
typedef unsigned short u16x4 __attribute__((ext_vector_type(4)));

#define SRU_B 16
#define SRU_T 2048
#define SRU_D 1024
#define SRU_L 4
#define SRU_N 3072          // 3*D
#define TC 512              // T-chunk
#define MC (TC * SRU_B)     // 8192 rows per GEMM chunk

__device__ __forceinline__ unsigned short f2bf(float x) {
  unsigned int u = __float_as_uint(x);
  u += 0x7FFFu + ((u >> 16) & 1u);   // RNE
  return (unsigned short)(u >> 16);
}
__device__ __forceinline__ float bf2f(unsigned short h) {
  return __uint_as_float(((unsigned int)h) << 16);
}

__device__ __forceinline__ void mfma_bf16(f32x4& c, s16x8 a, s16x8 b) {
  asm("v_mfma_f32_16x16x32_bf16 %0, %1, %2, %0" : "+v"(c) : "v"(a), "v"(b));
}

#define GLDS(g, l) __builtin_amdgcn_global_load_lds(                      \
    (const __attribute__((address_space(1))) void*)(g),                   \
    (__attribute__((address_space(3))) void*)(l), 16, 0, 0)

// ---- W convert: [L][D][3D] f32 -> transposed [L][3D][D] bf16 hi/lo ----
__global__ void convert_w_kernel(const float* __restrict__ W,
                                 unsigned short* __restrict__ Wth,
                                 unsigned short* __restrict__ Wtl) {
  __shared__ float tile[32][33];
  const int l = blockIdx.z;
  const int n0 = blockIdx.x * 32, k0 = blockIdx.y * 32;
  const int tx = threadIdx.x & 31, ty = threadIdx.x >> 5; // ty 0..7
  const float* Wl = W + (size_t)l * SRU_D * SRU_N;
#pragma unroll
  for (int i = 0; i < 32; i += 8)
    tile[ty + i][tx] = Wl[(size_t)(k0 + ty + i) * SRU_N + n0 + tx];
  __syncthreads();
  const size_t ob = (size_t)l * SRU_N * SRU_D;
#pragma unroll
  for (int i = 0; i < 32; i += 8) {
    float v = tile[tx][ty + i];
    size_t o = ob + (size_t)(n0 + ty + i) * SRU_D + k0 + tx;
    unsigned short hi = f2bf(v);
    Wth[o] = hi;
    Wtl[o] = f2bf(v - bf2f(hi));
  }
}

// ---- x convert: [B][T][D] f32 -> H [T][B][D] bf16 hi/lo ----
__global__ void convert_x_kernel(const float* __restrict__ x,
                                 unsigned short* __restrict__ Hh,
                                 unsigned short* __restrict__ Hl) {
  const int bt = blockIdx.x;           // b*T + t
  const int b = bt >> 11, t = bt & 2047;
  const f32x4* xr = (const f32x4*)(x + (size_t)bt * SRU_D);
  f32x4 v = xr[threadIdx.x];
  u16x4 hi, lo;
#pragma unroll
  for (int j = 0; j < 4; ++j) {
    unsigned short h = f2bf(v[j]);
    hi[j] = h;
    lo[j] = f2bf(v[j] - bf2f(h));
  }
  size_t ho = ((size_t)t * SRU_B + b) * SRU_D;
  ((u16x4*)(Hh + ho))[threadIdx.x] = hi;
  ((u16x4*)(Hl + ho))[threadIdx.x] = lo;
}

// ---- GEMM: U[MC][3072] = A[MC][1024] * W^T, 3-product split-bf16 ----
// A rows = chunk of H ([T,B,D] flattened). B^T = Wt [N][K].
__global__ __launch_bounds__(256) void gemm3_kernel(
    const unsigned short* __restrict__ Ah, const unsigned short* __restrict__ Al,
    const unsigned short* __restrict__ Bh, const unsigned short* __restrict__ Bl,
    float* __restrict__ U) {
  __shared__ unsigned short lAh[4096], lAl[4096], lBh[4096], lBl[4096];
  const int tid = threadIdx.x;
  const int bn = blockIdx.x, bm = blockIdx.y;
  const int lane = tid & 63, wid = tid >> 6;
  const int wm = (wid >> 1) * 64, wn = (wid & 1) * 64;
  const int fr = lane & 15, fkb = (lane >> 4) * 8;

  f32x4 acc[4][4] = {};

  const int sr = tid >> 2;          // staging row 0..63
  const int sc = (tid & 3) * 8;     // staging col (elements)
  const unsigned short* gAh = Ah + (size_t)(bm * 128 + sr) * 1024 + sc;
  const unsigned short* gAl = Al + (size_t)(bm * 128 + sr) * 1024 + sc;
  const unsigned short* gBh = Bh + (size_t)(bn * 128 + sr) * 1024 + sc;
  const unsigned short* gBl = Bl + (size_t)(bn * 128 + sr) * 1024 + sc;

  for (int k0 = 0; k0 < 1024; k0 += 32) {
    GLDS(gAh + k0,         &lAh[wid * 512]);
    GLDS(gAh + 65536 + k0, &lAh[2048 + wid * 512]);
    GLDS(gAl + k0,         &lAl[wid * 512]);
    GLDS(gAl + 65536 + k0, &lAl[2048 + wid * 512]);
    GLDS(gBh + k0,         &lBh[wid * 512]);
    GLDS(gBh + 65536 + k0, &lBh[2048 + wid * 512]);
    GLDS(gBl + k0,         &lBl[wid * 512]);
    GLDS(gBl + 65536 + k0, &lBl[2048 + wid * 512]);
    __syncthreads();
    s16x8 ah[4], al[4], bh[4], bl[4];
#pragma unroll
    for (int i = 0; i < 4; ++i) {
      ah[i] = *(const s16x8*)&lAh[(wm + i * 16 + fr) * 32 + fkb];
      al[i] = *(const s16x8*)&lAl[(wm + i * 16 + fr) * 32 + fkb];
      bh[i] = *(const s16x8*)&lBh[(wn + i * 16 + fr) * 32 + fkb];
      bl[i] = *(const s16x8*)&lBl[(wn + i * 16 + fr) * 32 + fkb];
    }
#pragma unroll
    for (int mi = 0; mi < 4; ++mi)
#pragma unroll
      for (int ni = 0; ni < 4; ++ni) {
        mfma_bf16(acc[mi][ni], ah[mi], bh[ni]);
        mfma_bf16(acc[mi][ni], ah[mi], bl[ni]);
        mfma_bf16(acc[mi][ni], al[mi], bh[ni]);
      }
    __syncthreads();
  }
  const int orow = bm * 128 + wm + (lane >> 4) * 4;
  const int ocol = bn * 128 + wn + fr;
#pragma unroll
  for (int mi = 0; mi < 4; ++mi)
#pragma unroll
    for (int ni = 0; ni < 4; ++ni)
#pragma unroll
      for (int r = 0; r < 4; ++r)
        U[(size_t)(orow + mi * 16 + r) * SRU_N + ocol + ni * 16] = acc[mi][ni][r];
}

// ---- scan + highway, one T-chunk, in-place H update ----
__global__ __launch_bounds__(64) void scan_kernel(
    const float* __restrict__ U, const float* __restrict__ bias,
    unsigned short* __restrict__ Hh, unsigned short* __restrict__ Hl,
    float* __restrict__ cst, int t0) {
  const int b = blockIdx.x >> 4;
  const int d = ((blockIdx.x & 15) << 6) + threadIdx.x;
  float c = (t0 == 0) ? 0.f : cst[(b << 10) + d];
  const float bf = bias[d], br = bias[SRU_D + d];
#pragma unroll 2
  for (int t = 0; t < TC; ++t) {
    const size_t ub = (size_t)(t * SRU_B + b) * SRU_N;
    float xt = U[ub + d];
    float zf = U[ub + SRU_D + d] + bf;
    float zr = U[ub + 2 * SRU_D + d] + br;
    float f = 1.f / (1.f + __expf(-zf));
    float r = 1.f / (1.f + __expf(-zr));
    c = f * c + (1.f - f) * xt;
    const size_t hidx = ((size_t)((t0 + t) * SRU_B + b) << 10) + d;
    float h = bf2f(Hh[hidx]) + bf2f(Hl[hidx]);
    float e = __expf(-2.f * fabsf(c));
    float th = (1.f - e) / (1.f + e);
    th = copysignf(th, c);
    float o = r * th + (1.f - r) * h;
    unsigned short oh = f2bf(o);
    Hh[hidx] = oh;
    Hl[hidx] = f2bf(o - bf2f(oh));
  }
  cst[(b << 10) + d] = c;
}

// ---- final gather: out[b] = h[lengths[b]-1, b, :] ----
__global__ void select_kernel(const unsigned short* __restrict__ Hh,
                              const unsigned short* __restrict__ Hl,
                              const int* __restrict__ lengths,
                              float* __restrict__ out) {
  const int b = blockIdx.x;
  const int t = lengths[b] - 1;
#pragma unroll
  for (int j = 0; j < 4; ++j) {
    int d = threadIdx.x + j * 256;
    size_t idx = ((size_t)(t * SRU_B + b) << 10) + d;
    out[(b << 10) + d] = bf2f(Hh[idx]) + bf2f(Hl[idx]);
  }
}

extern "C" void kernel_launch(void* const* d_in, const int* in_sizes, int n_in,
                              void* d_out, int out_size, void* d_ws, size_t ws_size,
                              hipStream_t stream) {
  const float* x = (const float*)d_in[0];
  const int* lengths = (const int*)d_in[1];
  const float* W = (const float*)d_in[2];
  const float* bias = (const float*)d_in[3];
  float* out = (float*)d_out;

  char* ws = (char*)d_ws;
  size_t off = 0;
  auto alloc = [&](size_t n) { void* p = ws + off; off += (n + 255) & ~(size_t)255; return p; };
  unsigned short* Hh  = (unsigned short*)alloc((size_t)SRU_T * SRU_B * SRU_D * 2); // 64MB
  unsigned short* Hl  = (unsigned short*)alloc((size_t)SRU_T * SRU_B * SRU_D * 2); // 64MB
  unsigned short* Wth = (unsigned short*)alloc((size_t)SRU_L * SRU_N * SRU_D * 2); // 24MB
  unsigned short* Wtl = (unsigned short*)alloc((size_t)SRU_L * SRU_N * SRU_D * 2); // 24MB
  float* U   = (float*)alloc((size_t)MC * SRU_N * 4);                              // 96MB
  float* cst = (float*)alloc((size_t)SRU_B * SRU_D * 4);                           // 64KB

  hipLaunchKernelGGL(convert_w_kernel, dim3(SRU_N / 32, SRU_D / 32, SRU_L), dim3(256), 0, stream,
                     W, Wth, Wtl);
  hipLaunchKernelGGL(convert_x_kernel, dim3(SRU_B * SRU_T), dim3(256), 0, stream, x, Hh, Hl);

  for (int l = 0; l < SRU_L; ++l) {
    const unsigned short* Bh = Wth + (size_t)l * SRU_N * SRU_D;
    const unsigned short* Bl = Wtl + (size_t)l * SRU_N * SRU_D;
    for (int ch = 0; ch < SRU_T / TC; ++ch) {
      size_t arow0 = (size_t)ch * MC;
      hipLaunchKernelGGL(gemm3_kernel, dim3(SRU_N / 128, MC / 128), dim3(256), 0, stream,
                         Hh + arow0 * SRU_D, Hl + arow0 * SRU_D, Bh, Bl, U);
      hipLaunchKernelGGL(scan_kernel, dim3(256), dim3(64), 0, stream,
                         U, bias + (size_t)l * 2 * SRU_D, Hh, Hl, cst, ch * TC);
    }
  }
  hipLaunchKernelGGL(select_kernel, dim3(SRU_B), dim3(256), 0, stream, Hh, Hl, lengths, out);
}

// Round 2
// 4179.555 us; speedup vs baseline: 1.2954x; 1.2954x over previous
//
#include <hip/hip_runtime.h>

// SRU forward, MI355X. B=16, T=2048, D=1024, L=4.
// h stored as bf16 hi/lo split pair (f32-equivalent precision, MFMA-consumable).
// GEMM: U = h @ W_l via 3-product split-bf16 MFMA (AhBh + AhBl + AlBh), f32 acc.
// Scan: sequential over T per (b,d) chain, software-pipelined UB=16 batch
// prefetch (loads are independent of the carried state -> deep in-flight).

typedef float f32x4 __attribute__((ext_vector_type(4)));
typedef short s16x8 __attribute__((ext_vector_type(8)));
typedef unsigned short u16x4 __attribute__((ext_vector_type(4)));

#define SRU_B 16
#define SRU_T 2048
#define SRU_D 1024
#define SRU_L 4
#define SRU_N 3072          // 3*D
#define TC 512              // T-chunk
#define MC (TC * SRU_B)     // 8192 rows per GEMM chunk
#define UB 16               // scan pipeline batch (timesteps)

__device__ __forceinline__ unsigned short f2bf(float x) {
  unsigned int u = __float_as_uint(x);
  u += 0x7FFFu + ((u >> 16) & 1u);   // RNE
  return (unsigned short)(u >> 16);
}
__device__ __forceinline__ float bf2f(unsigned short h) {
  return __uint_as_float(((unsigned int)h) << 16);
}

__device__ __forceinline__ void mfma_bf16(f32x4& c, s16x8 a, s16x8 b) {
  asm("v_mfma_f32_16x16x32_bf16 %0, %1, %2, %0" : "+v"(c) : "v"(a), "v"(b));
}

#define GLDS(g, l) __builtin_amdgcn_global_load_lds(                      \
    (const __attribute__((address_space(1))) void*)(g),                   \
    (__attribute__((address_space(3))) void*)(l), 16, 0, 0)

// ---- W convert: [L][D][3D] f32 -> transposed [L][3D][D] bf16 hi/lo ----
__global__ void convert_w_kernel(const float* __restrict__ W,
                                 unsigned short* __restrict__ Wth,
                                 unsigned short* __restrict__ Wtl) {
  __shared__ float tile[32][33];
  const int l = blockIdx.z;
  const int n0 = blockIdx.x * 32, k0 = blockIdx.y * 32;
  const int tx = threadIdx.x & 31, ty = threadIdx.x >> 5; // ty 0..7
  const float* Wl = W + (size_t)l * SRU_D * SRU_N;
#pragma unroll
  for (int i = 0; i < 32; i += 8)
    tile[ty + i][tx] = Wl[(size_t)(k0 + ty + i) * SRU_N + n0 + tx];
  __syncthreads();
  const size_t ob = (size_t)l * SRU_N * SRU_D;
#pragma unroll
  for (int i = 0; i < 32; i += 8) {
    float v = tile[tx][ty + i];
    size_t o = ob + (size_t)(n0 + ty + i) * SRU_D + k0 + tx;
    unsigned short hi = f2bf(v);
    Wth[o] = hi;
    Wtl[o] = f2bf(v - bf2f(hi));
  }
}

// ---- x convert: [B][T][D] f32 -> H [T][B][D] bf16 hi/lo ----
__global__ void convert_x_kernel(const float* __restrict__ x,
                                 unsigned short* __restrict__ Hh,
                                 unsigned short* __restrict__ Hl) {
  const int bt = blockIdx.x;           // b*T + t
  const int b = bt >> 11, t = bt & 2047;
  const f32x4* xr = (const f32x4*)(x + (size_t)bt * SRU_D);
  f32x4 v = xr[threadIdx.x];
  u16x4 hi, lo;
#pragma unroll
  for (int j = 0; j < 4; ++j) {
    unsigned short h = f2bf(v[j]);
    hi[j] = h;
    lo[j] = f2bf(v[j] - bf2f(h));
  }
  size_t ho = ((size_t)t * SRU_B + b) * SRU_D;
  ((u16x4*)(Hh + ho))[threadIdx.x] = hi;
  ((u16x4*)(Hl + ho))[threadIdx.x] = lo;
}

// ---- GEMM: U[MC][3072] = A[MC][1024] * W^T, 3-product split-bf16 ----
// A rows = chunk of H ([T,B,D] flattened). B^T = Wt [N][K].
__global__ __launch_bounds__(256) void gemm3_kernel(
    const unsigned short* __restrict__ Ah, const unsigned short* __restrict__ Al,
    const unsigned short* __restrict__ Bh, const unsigned short* __restrict__ Bl,
    float* __restrict__ U) {
  __shared__ unsigned short lAh[4096], lAl[4096], lBh[4096], lBl[4096];
  const int tid = threadIdx.x;
  const int bn = blockIdx.x, bm = blockIdx.y;
  const int lane = tid & 63, wid = tid >> 6;
  const int wm = (wid >> 1) * 64, wn = (wid & 1) * 64;
  const int fr = lane & 15, fkb = (lane >> 4) * 8;

  f32x4 acc[4][4] = {};

  const int sr = tid >> 2;          // staging row 0..63
  const int sc = (tid & 3) * 8;     // staging col (elements)
  const unsigned short* gAh = Ah + (size_t)(bm * 128 + sr) * 1024 + sc;
  const unsigned short* gAl = Al + (size_t)(bm * 128 + sr) * 1024 + sc;
  const unsigned short* gBh = Bh + (size_t)(bn * 128 + sr) * 1024 + sc;
  const unsigned short* gBl = Bl + (size_t)(bn * 128 + sr) * 1024 + sc;

  for (int k0 = 0; k0 < 1024; k0 += 32) {
    GLDS(gAh + k0,         &lAh[wid * 512]);
    GLDS(gAh + 65536 + k0, &lAh[2048 + wid * 512]);
    GLDS(gAl + k0,         &lAl[wid * 512]);
    GLDS(gAl + 65536 + k0, &lAl[2048 + wid * 512]);
    GLDS(gBh + k0,         &lBh[wid * 512]);
    GLDS(gBh + 65536 + k0, &lBh[2048 + wid * 512]);
    GLDS(gBl + k0,         &lBl[wid * 512]);
    GLDS(gBl + 65536 + k0, &lBl[2048 + wid * 512]);
    __syncthreads();
    s16x8 ah[4], al[4], bh[4], bl[4];
#pragma unroll
    for (int i = 0; i < 4; ++i) {
      ah[i] = *(const s16x8*)&lAh[(wm + i * 16 + fr) * 32 + fkb];
      al[i] = *(const s16x8*)&lAl[(wm + i * 16 + fr) * 32 + fkb];
      bh[i] = *(const s16x8*)&lBh[(wn + i * 16 + fr) * 32 + fkb];
      bl[i] = *(const s16x8*)&lBl[(wn + i * 16 + fr) * 32 + fkb];
    }
#pragma unroll
    for (int mi = 0; mi < 4; ++mi)
#pragma unroll
      for (int ni = 0; ni < 4; ++ni) {
        mfma_bf16(acc[mi][ni], ah[mi], bh[ni]);
        mfma_bf16(acc[mi][ni], ah[mi], bl[ni]);
        mfma_bf16(acc[mi][ni], al[mi], bh[ni]);
      }
    __syncthreads();
  }
  const int orow = bm * 128 + wm + (lane >> 4) * 4;
  const int ocol = bn * 128 + wn + fr;
#pragma unroll
  for (int mi = 0; mi < 4; ++mi)
#pragma unroll
    for (int ni = 0; ni < 4; ++ni)
#pragma unroll
      for (int r = 0; r < 4; ++r)
        U[(size_t)(orow + mi * 16 + r) * SRU_N + ocol + ni * 16] = acc[mi][ni][r];
}

// ---- scan + highway, one T-chunk, in-place H update ----
// Software-pipelined: batch of UB timesteps' loads issued one batch ahead of
// the serial recurrence (loads are independent of carried state c).
__global__ __launch_bounds__(64) void scan_kernel(
    const float* __restrict__ U, const float* __restrict__ bias,
    unsigned short* __restrict__ Hh, unsigned short* __restrict__ Hl,
    float* __restrict__ cst, int t0) {
  const int b = blockIdx.x >> 4;
  const int d = ((blockIdx.x & 15) << 6) + threadIdx.x;
  float c = (t0 == 0) ? 0.f : cst[(b << 10) + d];
  const float bfv = bias[d], brv = bias[SRU_D + d];
  const float* Ub = U + (size_t)b * SRU_N + d;                       // + t*16*N
  unsigned short* phh = Hh + ((size_t)(t0 * SRU_B + b) << 10) + d;   // + t*16384
  unsigned short* phl = Hl + ((size_t)(t0 * SRU_B + b) << 10) + d;

  float xt_n[UB], zf_n[UB], zr_n[UB], hh_n[UB], hl_n[UB];
#pragma unroll
  for (int j = 0; j < UB; ++j) {
    const size_t uo = (size_t)j * SRU_B * SRU_N;
    xt_n[j] = Ub[uo];
    zf_n[j] = Ub[uo + SRU_D];
    zr_n[j] = Ub[uo + 2 * SRU_D];
    hh_n[j] = bf2f(phh[(size_t)j << 14]);
    hl_n[j] = bf2f(phl[(size_t)j << 14]);
  }

  for (int bt = 0; bt < TC / UB; ++bt) {
    float xt[UB], zf[UB], zr[UB], hv[UB];
#pragma unroll
    for (int j = 0; j < UB; ++j) {
      xt[j] = xt_n[j]; zf[j] = zf_n[j]; zr[j] = zr_n[j];
      hv[j] = hh_n[j] + hl_n[j];
    }
    if (bt + 1 < TC / UB) {        // issue next batch's loads before compute
      const float* Ub2 = Ub + (size_t)(bt + 1) * UB * SRU_B * SRU_N;
      const unsigned short* phh2 = phh + ((size_t)((bt + 1) * UB) << 14);
      const unsigned short* phl2 = phl + ((size_t)((bt + 1) * UB) << 14);
#pragma unroll
      for (int j = 0; j < UB; ++j) {
        const size_t uo = (size_t)j * SRU_B * SRU_N;
        xt_n[j] = Ub2[uo];
        zf_n[j] = Ub2[uo + SRU_D];
        zr_n[j] = Ub2[uo + 2 * SRU_D];
        hh_n[j] = bf2f(phh2[(size_t)j << 14]);
        hl_n[j] = bf2f(phl2[(size_t)j << 14]);
      }
    }
    unsigned short* wh = phh + ((size_t)(bt * UB) << 14);
    unsigned short* wl = phl + ((size_t)(bt * UB) << 14);
#pragma unroll
    for (int j = 0; j < UB; ++j) {
      float f = 1.f / (1.f + __expf(-(zf[j] + bfv)));
      float r = 1.f / (1.f + __expf(-(zr[j] + brv)));
      c = f * c + (1.f - f) * xt[j];
      float e = __expf(-2.f * fabsf(c));
      float th = copysignf((1.f - e) / (1.f + e), c);
      float o = r * th + (1.f - r) * hv[j];
      unsigned short oh = f2bf(o);
      wh[(size_t)j << 14] = oh;
      wl[(size_t)j << 14] = f2bf(o - bf2f(oh));
    }
  }
  cst[(b << 10) + d] = c;
}

// ---- final gather: out[b] = h[lengths[b]-1, b, :] ----
__global__ void select_kernel(const unsigned short* __restrict__ Hh,
                              const unsigned short* __restrict__ Hl,
                              const int* __restrict__ lengths,
                              float* __restrict__ out) {
  const int b = blockIdx.x;
  const int t = lengths[b] - 1;
#pragma unroll
  for (int j = 0; j < 4; ++j) {
    int d = threadIdx.x + j * 256;
    size_t idx = ((size_t)(t * SRU_B + b) << 10) + d;
    out[(b << 10) + d] = bf2f(Hh[idx]) + bf2f(Hl[idx]);
  }
}

extern "C" void kernel_launch(void* const* d_in, const int* in_sizes, int n_in,
                              void* d_out, int out_size, void* d_ws, size_t ws_size,
                              hipStream_t stream) {
  const float* x = (const float*)d_in[0];
  const int* lengths = (const int*)d_in[1];
  const float* W = (const float*)d_in[2];
  const float* bias = (const float*)d_in[3];
  float* out = (float*)d_out;

  char* ws = (char*)d_ws;
  size_t off = 0;
  auto alloc = [&](size_t n) { void* p = ws + off; off += (n + 255) & ~(size_t)255; return p; };
  unsigned short* Hh  = (unsigned short*)alloc((size_t)SRU_T * SRU_B * SRU_D * 2); // 64MB
  unsigned short* Hl  = (unsigned short*)alloc((size_t)SRU_T * SRU_B * SRU_D * 2); // 64MB
  unsigned short* Wth = (unsigned short*)alloc((size_t)SRU_L * SRU_N * SRU_D * 2); // 24MB
  unsigned short* Wtl = (unsigned short*)alloc((size_t)SRU_L * SRU_N * SRU_D * 2); // 24MB
  float* U   = (float*)alloc((size_t)MC * SRU_N * 4);                              // 96MB
  float* cst = (float*)alloc((size_t)SRU_B * SRU_D * 4);                           // 64KB

  hipLaunchKernelGGL(convert_w_kernel, dim3(SRU_N / 32, SRU_D / 32, SRU_L), dim3(256), 0, stream,
                     W, Wth, Wtl);
  hipLaunchKernelGGL(convert_x_kernel, dim3(SRU_B * SRU_T), dim3(256), 0, stream, x, Hh, Hl);

  for (int l = 0; l < SRU_L; ++l) {
    const unsigned short* Bh = Wth + (size_t)l * SRU_N * SRU_D;
    const unsigned short* Bl = Wtl + (size_t)l * SRU_N * SRU_D;
    for (int ch = 0; ch < SRU_T / TC; ++ch) {
      size_t arow0 = (size_t)ch * MC;
      hipLaunchKernelGGL(gemm3_kernel, dim3(SRU_N / 128, MC / 128), dim3(256), 0, stream,
                         Hh + arow0 * SRU_D, Hl + arow0 * SRU_D, Bh, Bl, U);
      hipLaunchKernelGGL(scan_kernel, dim3(256), dim3(64), 0, stream,
                         U, bias + (size_t)l * 2 * SRU_D, Hh, Hl, cst, ch * TC);
    }
  }
  hipLaunchKernelGGL(select_kernel, dim3(SRU_B), dim3(256), 0, stream, Hh, Hl, lengths, out);
}